// Round 10
// baseline (1905.088 us; speedup 1.0000x reference)
//
#include <hip/hip_runtime.h>
#include <hip/hip_bf16.h>

// ---------- types ----------
typedef __attribute__((ext_vector_type(8))) short s16x8;
typedef __attribute__((ext_vector_type(4))) short s16x4;
typedef __attribute__((ext_vector_type(8))) __bf16 bf16x8;
typedef __attribute__((ext_vector_type(4))) float f32x4;

__device__ __forceinline__ float b2f(short s) {
  union { float f; unsigned u; } x;
  x.u = ((unsigned)(unsigned short)s) << 16;
  return x.f;
}
__device__ __forceinline__ short f2b(float f) {
  union { float f; unsigned u; } x;
  x.f = f;
  unsigned r = x.u + 0x7fff + ((x.u >> 16) & 1);  // RNE
  return (short)(r >> 16);
}
__device__ __forceinline__ bf16x8 asbf(s16x8 v) {
  union { s16x8 s; bf16x8 b; } u; u.s = v; return u.b;
}

#define GLD16(g, l) __builtin_amdgcn_global_load_lds( \
    (const __attribute__((address_space(1))) void*)(g), \
    (__attribute__((address_space(3))) void*)(l), 16, 0, 0)

#define WAITB(N) do { \
  asm volatile("s_waitcnt vmcnt(" #N ")" ::: "memory"); \
  __builtin_amdgcn_s_barrier(); \
  asm volatile("" ::: "memory"); \
} while (0)

// ---------- weight transpose + fp32->bf16 : out[c][r] = in[r][c] ----------
__global__ __launch_bounds__(256) void transpose_cvt(
    const float* __restrict__ in, short* __restrict__ out, int R, int C) {
  __shared__ float tile[32][33];
  const int tx = threadIdx.x & 31, ty = threadIdx.x >> 5;  // 32x8
  const int c0 = blockIdx.x * 32, r0 = blockIdx.y * 32;
  #pragma unroll
  for (int i = 0; i < 32; i += 8)
    tile[ty + i][tx] = in[(size_t)(r0 + ty + i) * C + c0 + tx];
  __syncthreads();
  #pragma unroll
  for (int i = 0; i < 32; i += 8)
    out[(size_t)(c0 + ty + i) * R + r0 + tx] = f2b(tile[tx][ty + i]);
}

// ---------- layernorm: fp32 [rows][1024] -> bf16 ----------
__global__ __launch_bounds__(256) void ln_kernel(
    const float* __restrict__ x, const float* __restrict__ gw,
    const float* __restrict__ gb, short* __restrict__ out) {
  const int row = blockIdx.x;
  const int tid = threadIdx.x;
  const float4 v = ((const float4*)(x + (size_t)row * 1024))[tid];
  float s = v.x + v.y + v.z + v.w;
  float s2 = v.x * v.x + v.y * v.y + v.z * v.z + v.w * v.w;
  #pragma unroll
  for (int o = 32; o > 0; o >>= 1) {
    s += __shfl_xor(s, o);
    s2 += __shfl_xor(s2, o);
  }
  __shared__ float red[2][4];
  const int lane = tid & 63, wid = tid >> 6;
  if (lane == 0) { red[0][wid] = s; red[1][wid] = s2; }
  __syncthreads();
  s = red[0][0] + red[0][1] + red[0][2] + red[0][3];
  s2 = red[1][0] + red[1][1] + red[1][2] + red[1][3];
  const float mu = s * (1.f / 1024.f);
  const float rstd = rsqrtf(s2 * (1.f / 1024.f) - mu * mu + 1e-5f);
  const float4 wv4 = ((const float4*)gw)[tid];
  const float4 bv4 = ((const float4*)gb)[tid];
  s16x4 o4;
  o4.x = f2b((v.x - mu) * rstd * wv4.x + bv4.x);
  o4.y = f2b((v.y - mu) * rstd * wv4.y + bv4.y);
  o4.z = f2b((v.z - mu) * rstd * wv4.z + bv4.z);
  o4.w = f2b((v.w - mu) * rstd * wv4.w + bv4.w);
  *(s16x4*)(out + (size_t)row * 1024 + tid * 4) = o4;
}

// ---------- 256x256 bf16 MFMA GEMM, 4 waves x 128x128 (fat-wave) ----------
// r9 diagnosis: 8x(128x64) waves make LDS deliver 196KB/tile for 64KB of
// distinct operands (3x redundancy) -> LDS-BW wall at ~40% MfmaUtil, schedule-
// invariant (r3/r6/r7/r9 all ~230us). Fix: 4 waves x 128x128 tiles = 33% less
// LDS bytes/FLOP; acc[8][8]=256 regs fits the 512-reg budget at 1 wave/SIMD
// (launch_bounds(256,1)); each SIMD self-paced, 2 block barriers/tile.
// LDS geometry + XOR swizzle byte-identical to r3 (write slot s0^(g&7) ==
// read slot ((row&1)<<2|fq)^(g&7), both-sides proven).
// Ledger: +8(kh0 t+1) | KS0 | +8(kh1 t+1) | WAITB(16) proves kh1(t) | KS1 |
//         WAITB(8) proves kh0(t+1). Max 24 in flight; never drained.

enum { EPI_QKV = 0, EPI_RES = 1, EPI_GELU = 2, EPI_FC2 = 3 };

#define PHASEKS(BUFB, KS) do { \
    bf16x8 af[8], bfv[8]; \
    _Pragma("unroll") \
    for (int ni = 0; ni < 8; ni++) { \
      const int row = wnCol + ni * 16 + fr; \
      const int g = row >> 1; \
      const int s = (((row & 1) << 2) | fq) ^ (g & 7); \
      bfv[ni] = *(const bf16x8*)(ldsc + (BUFB) + 32768 + (KS) * 16384 + g * 128 + s * 16); \
    } \
    _Pragma("unroll") \
    for (int mi = 0; mi < 8; mi++) { \
      const int row = wmRow + mi * 16 + fr; \
      const int g = row >> 1; \
      const int s = (((row & 1) << 2) | fq) ^ (g & 7); \
      af[mi] = *(const bf16x8*)(ldsc + (BUFB) + (KS) * 16384 + g * 128 + s * 16); \
    } \
    __builtin_amdgcn_s_setprio(1); \
    _Pragma("unroll") \
    for (int mi = 0; mi < 8; mi++) \
      _Pragma("unroll") \
      for (int ni = 0; ni < 8; ni++) \
        acc[mi][ni] = __builtin_amdgcn_mfma_f32_16x16x32_bf16( \
            af[mi], bfv[ni], acc[mi][ni], 0, 0, 0); \
    __builtin_amdgcn_s_setprio(0); \
  } while (0)

template <int EPI>
__global__ __launch_bounds__(256, 1) void gemm256(
    const short* __restrict__ A, int lda,
    const short* __restrict__ Bt, int K, int ldo, int gx,
    const float* __restrict__ bias,
    const float* __restrict__ resid,
    void* __restrict__ outp) {
  __shared__ alignas(16) short lds[65536];  // 128 KiB
  const int tid = threadIdx.x;
  const int lane = tid & 63, wave = tid >> 6;  // 4 waves
  // T1: bijective XCD swizzle (grid % 8 == 0 for all launches)
  const int cpx = (int)gridDim.x >> 3;
  const int bid = ((int)blockIdx.x & 7) * cpx + ((int)blockIdx.x >> 3);
  const int bm = (bid % gx) * 256;  // fast index (r3-proven mapping)
  const int bn = (bid / gx) * 256;
  const int wmRow = (wave >> 1) * 128;  // 2 M-groups
  const int wnCol = (wave & 1) * 128;   // 2 N-groups
  const int fr = lane & 15, fq = lane >> 4;

  // staging constants: inverse-swizzled global source, linear LDS dest
  const int sg = tid >> 3;               // 0..31
  const int s0 = (tid & 7) ^ (sg & 7);
  const int srow = 2 * sg + (s0 >> 2);   // 0..63 per GLD16 unit
  const int scol = (s0 & 3) * 8;
  const int sdst = tid * 16;             // 4KB per unit

  const char* ldsc = (const char*)lds;
  char* ldsw = (char*)lds;

  f32x4 acc[8][8] = {};

  auto stageA = [&](int bufb, int kh, int kk) {
    const short* g = A + (size_t)(bm + srow) * lda + kk + kh * 32 + scol;
    char* l = ldsw + bufb + kh * 16384 + sdst;
    GLD16(g, l);
    GLD16(g + (size_t)64 * lda, l + 4096);
    GLD16(g + (size_t)128 * lda, l + 8192);
    GLD16(g + (size_t)192 * lda, l + 12288);
  };
  auto stageB = [&](int bufb, int kh, int kk) {
    const short* g = Bt + (size_t)(bn + srow) * K + kk + kh * 32 + scol;
    char* l = ldsw + bufb + 32768 + kh * 16384 + sdst;
    GLD16(g, l);
    GLD16(g + (size_t)64 * K, l + 4096);
    GLD16(g + (size_t)128 * K, l + 8192);
    GLD16(g + (size_t)192 * K, l + 12288);
  };

  const int NT = K >> 6;
  // prologue: full tile 0 into buf0; WAITB(8) proves kh0(0), kh1(0) in flight
  stageA(0, 0, 0);
  stageB(0, 0, 0);
  stageA(0, 1, 0);
  stageB(0, 1, 0);
  WAITB(8);

  int buf = 0;
  for (int t = 0; t < NT; ++t) {
    const int kkn = (t + 1 < NT) ? ((t + 1) << 6) : 0;  // clamp keeps counts uniform
    const int nb = buf ^ 65536;
    stageA(nb, 0, kkn);   // +8: kh0(t+1)
    stageB(nb, 0, kkn);
    PHASEKS(buf, 0);      // KS0 (kh0(t) proven)
    stageA(nb, 1, kkn);   // +8: kh1(t+1)
    stageB(nb, 1, kkn);
    WAITB(16);            // proves kh1(t); 16 of t+1 in flight
    PHASEKS(buf, 1);      // KS1
    WAITB(8);             // proves kh0(t+1); kh1(t+1) in flight
    buf = nb;
  }
  asm volatile("s_waitcnt vmcnt(0)" ::: "memory");

  // epilogue: row = bm+wmRow+mi*16+fq*4+r ; col = bn+wnCol+ni*16+fr
  const int row0 = bm + wmRow + fq * 4;
  const int col0 = bn + wnCol + fr;
  #pragma unroll
  for (int mi = 0; mi < 8; mi++) {
    #pragma unroll
    for (int ni = 0; ni < 8; ni++) {
      const int col = col0 + ni * 16;
      #pragma unroll
      for (int r = 0; r < 4; r++) {
        const int row = row0 + mi * 16 + r;
        float v = acc[mi][ni][r];
        if constexpr (EPI == EPI_QKV) {
          if (col < 2048) v = (v > 0.f) ? (v + 1.f) : __expf(v);  // phi = elu+1
          ((short*)outp)[(size_t)row * ldo + col] = f2b(v);
        } else if constexpr (EPI == EPI_RES) {
          ((float*)outp)[(size_t)row * ldo + col] =
              v + resid[(size_t)row * ldo + col];
        } else if constexpr (EPI == EPI_GELU) {
          v += bias[col];
          v = 0.5f * v * (1.f + erff(v * 0.70710678118654752f));
          ((short*)outp)[(size_t)row * ldo + col] = f2b(v);
        } else {  // EPI_FC2
          v += bias[col] + resid[(size_t)row * ldo + col];
          ((float*)outp)[(size_t)row * ldo + col] = v;
        }
      }
    }
  }
}

// ---------- kv partial reduce: per (b,h,chunk) 64x64 outer-product partial ----------
// grid 2048 = 64 bh * 32 chunks of 256 rows
__global__ __launch_bounds__(256) void kv_reduce(
    const short* __restrict__ qkv, float* __restrict__ kv_part,
    float* __restrict__ ksum_part) {
  const int blk = blockIdx.x;
  const int bh = blk >> 5, chunk = blk & 31;
  const int b = bh >> 4, h = bh & 15;
  const size_t rowbase = (size_t)b * 8192 + (size_t)chunk * 256;
  const int kcol = 1024 + h * 64, vcol = 2048 + h * 64;
  __shared__ short Kl[64][64];
  __shared__ short Vl[64][64];
  const int tid = threadIdx.x;
  const int dk = tid >> 2, dq = tid & 3;
  float acc[16] = {};
  float ks = 0.f;
  for (int t = 0; t < 4; t++) {
    #pragma unroll
    for (int i = 0; i < 2; i++) {
      const int s = i * 256 + tid;
      const int r = s >> 3, seg = (s & 7) * 8;
      const size_t g = (rowbase + t * 64 + r) * 3072;
      *(s16x8*)&Kl[r][seg] = *(const s16x8*)&qkv[g + kcol + seg];
      *(s16x8*)&Vl[r][seg] = *(const s16x8*)&qkv[g + vcol + seg];
    }
    __syncthreads();
    for (int n = 0; n < 64; n++) {
      const float kval = b2f(Kl[n][dk]);
      if (dq == 0) ks += kval;
      const s16x8 v0 = *(const s16x8*)&Vl[n][dq * 16];
      const s16x8 v1 = *(const s16x8*)&Vl[n][dq * 16 + 8];
      #pragma unroll
      for (int j = 0; j < 8; j++) {
        acc[j] = fmaf(kval, b2f(v0[j]), acc[j]);
        acc[8 + j] = fmaf(kval, b2f(v1[j]), acc[8 + j]);
      }
    }
    __syncthreads();
  }
  float* dst = kv_part + (size_t)blk * 4096 + dk * 64 + dq * 16;
  #pragma unroll
  for (int j = 0; j < 16; j++) dst[j] = acc[j];
  if (dq == 0) ksum_part[(size_t)blk * 64 + dk] = ks;
}

// ---------- kv finalize: reduce 32 partials -> bf16 kv^T, pre-swizzled ----------
__global__ __launch_bounds__(256) void kv_finalize(
    const float* __restrict__ kv_part, const float* __restrict__ ksum_part,
    short* __restrict__ kvT_g, float* __restrict__ ksum_f) {
  const int bh = blockIdx.x >> 2, dg = blockIdx.x & 3;
  const int tid = threadIdx.x;
  const int e = tid & 63, j4 = tid >> 6;
  const int d0 = dg * 16 + j4 * 4;
  float a0 = 0.f, a1 = 0.f, a2 = 0.f, a3 = 0.f;
  const float* base = kv_part + (size_t)bh * 32 * 4096 + d0 * 64 + e;
  for (int c = 0; c < 32; c++) {
    const float* p = base + (size_t)c * 4096;
    a0 += p[0]; a1 += p[64]; a2 += p[128]; a3 += p[192];
  }
  s16x4 o; o.x = f2b(a0); o.y = f2b(a1); o.z = f2b(a2); o.w = f2b(a3);
  char* dstb = (char*)(kvT_g + (size_t)bh * 4096);
  *(s16x4*)(dstb + e * 128 + ((2 * d0) ^ ((e & 7) << 4))) = o;
  if (tid < 16) {
    const int d = dg * 16 + tid;
    float s = 0.f;
    for (int c = 0; c < 32; c++)
      s += ksum_part[((size_t)bh * 32 + c) * 64 + d];
    ksum_f[bh * 64 + d] = s;
  }
}

// ---------- attention apply via MFMA: ao = (Q @ kv) / (Q . ksum + eps) ----------
__global__ __launch_bounds__(256) void attn_apply_mfma(
    const short* __restrict__ qkv, const short* __restrict__ kvT_g,
    const float* __restrict__ ksum_f, short* __restrict__ ao) {
  __shared__ alignas(16) short kvs[4096];
  __shared__ float ksl[64];
  const int blk = blockIdx.x;
  const int bh = blk >> 5, rc = blk & 31;
  const int b = bh >> 4, h = bh & 15;
  const int tid = threadIdx.x, lane = tid & 63, w = tid >> 6;
  const int fr = lane & 15, fq = lane >> 4;

  GLD16(kvT_g + (size_t)bh * 4096 + tid * 8, (char*)kvs + tid * 16);
  GLD16(kvT_g + (size_t)bh * 4096 + (256 + tid) * 8, (char*)kvs + (256 + tid) * 16);
  if (tid < 64) ksl[tid] = ksum_f[bh * 64 + tid];
  __syncthreads();

  bf16x8 bkv[4][2], bns[2];
  #pragma unroll
  for (int n = 0; n < 4; n++) {
    #pragma unroll
    for (int c = 0; c < 2; c++) {
      const int e = n * 16 + fr;
      const int byteoff = e * 128 + ((c * 64 + fq * 16) ^ ((e & 7) << 4));
      bkv[n][c] = *(const bf16x8*)((const char*)kvs + byteoff);
    }
  }
  #pragma unroll
  for (int c = 0; c < 2; c++) {
    s16x8 ts = {0, 0, 0, 0, 0, 0, 0, 0};
    if (fr == 0) {
      #pragma unroll
      for (int j = 0; j < 8; j++) ts[j] = f2b(ksl[c * 32 + fq * 8 + j]);
    }
    bns[c] = asbf(ts);
  }

  f32x4 acc[4][4] = {};
  f32x4 nacc[4] = {};
  const size_t rowbase = (size_t)b * 8192 + (size_t)rc * 256 + w * 64;
  const int qcol = h * 64;
  #pragma unroll
  for (int m = 0; m < 4; m++) {
    const short* qrow = qkv + (rowbase + m * 16 + fr) * 3072 + qcol + fq * 8;
    const bf16x8 a0 = *(const bf16x8*)qrow;
    const bf16x8 a1 = *(const bf16x8*)(qrow + 32);
    #pragma unroll
    for (int n = 0; n < 4; n++) {
      acc[m][n] = __builtin_amdgcn_mfma_f32_16x16x32_bf16(a0, bkv[n][0], acc[m][n], 0, 0, 0);
      acc[m][n] = __builtin_amdgcn_mfma_f32_16x16x32_bf16(a1, bkv[n][1], acc[m][n], 0, 0, 0);
    }
    nacc[m] = __builtin_amdgcn_mfma_f32_16x16x32_bf16(a0, bns[0], nacc[m], 0, 0, 0);
    nacc[m] = __builtin_amdgcn_mfma_f32_16x16x32_bf16(a1, bns[1], nacc[m], 0, 0, 0);
  }

  #pragma unroll
  for (int m = 0; m < 4; m++) {
    #pragma unroll
    for (int r = 0; r < 4; r++) {
      const float nv = __shfl(nacc[m][r], lane & 48) + 1e-6f;
      const float rn = 1.f / nv;
      const size_t row = rowbase + m * 16 + fq * 4 + r;
      #pragma unroll
      for (int n = 0; n < 4; n++)
        ao[row * 1024 + qcol + n * 16 + fr] = f2b(acc[m][n][r] * rn);
    }
  }
}

// ---------- launcher ----------
extern "C" void kernel_launch(void* const* d_in, const int* in_sizes, int n_in,
                              void* d_out, int out_size, void* d_ws, size_t ws_size,
                              hipStream_t stream) {
  (void)in_sizes; (void)n_in; (void)out_size; (void)ws_size;
  const float* src   = (const float*)d_in[0];
  const float* ln1_w = (const float*)d_in[1];
  const float* ln1_b = (const float*)d_in[2];
  const float* wq    = (const float*)d_in[3];
  const float* wk    = (const float*)d_in[4];
  const float* wv    = (const float*)d_in[5];
  const float* wo    = (const float*)d_in[6];
  const float* ln2_w = (const float*)d_in[7];
  const float* ln2_b = (const float*)d_in[8];
  const float* fc1_w = (const float*)d_in[9];
  const float* fc1_b = (const float*)d_in[10];
  const float* fc2_w = (const float*)d_in[11];
  const float* fc2_b = (const float*)d_in[12];

  char* ws = (char*)d_ws;
  short* wqkvT     = (short*)(ws + 0);            // [3072][1024] bf16
  short* woT       = (short*)(ws + 6291456);      // [1024][1024]
  short* fc1T      = (short*)(ws + 8388608);      // [4096][1024]
  short* fc2T      = (short*)(ws + 16777216);     // [1024][4096]
  short* kvT_g     = (short*)(ws + 25165824);     // [64][4096] bf16 swizzled
  float* ksum_f    = (float*)(ws + 25690112);     // [64][64]
  float* kv_part   = (float*)(ws + 25706496);     // [2048][4096] fp32
  float* ksum_part = (float*)(ws + 59260928);     // [2048][64]
  short* hbuf      = (short*)(ws + 59785216);     // [32768][1024] bf16 (h / ao / h2)
  float* src2      = (float*)(ws + 126894080);    // [32768][1024] fp32
  short* qkv       = (short*)(ws + 261111808);    // [32768][3072] bf16
  short* a1c       = (short*)(ws + 261111808);    // [16384][4096] bf16 (aliases qkv)
  // high-water: 462,438,400 bytes (< 503,447,552 proven in round 1)

  const dim3 tb(256);

  // weights -> bf16 transposed
  transpose_cvt<<<dim3(32, 32), tb, 0, stream>>>(wq, wqkvT, 1024, 1024);
  transpose_cvt<<<dim3(32, 32), tb, 0, stream>>>(wk, wqkvT + 1024 * 1024, 1024, 1024);
  transpose_cvt<<<dim3(32, 32), tb, 0, stream>>>(wv, wqkvT + 2048 * 1024, 1024, 1024);
  transpose_cvt<<<dim3(32, 32), tb, 0, stream>>>(wo, woT, 1024, 1024);
  transpose_cvt<<<dim3(128, 32), tb, 0, stream>>>(fc1_w, fc1T, 1024, 4096);
  transpose_cvt<<<dim3(32, 128), tb, 0, stream>>>(fc2_w, fc2T, 4096, 1024);

  // LN1: src -> h (bf16)
  ln_kernel<<<32768, tb, 0, stream>>>(src, ln1_w, ln1_b, hbuf);

  // QKV projection + phi on Q,K   (M=32768, N=3072, K=1024; gx=128)
  gemm256<EPI_QKV><<<dim3(1536), tb, 0, stream>>>(
      hbuf, 1024, wqkvT, 1024, 3072, 128, nullptr, nullptr, qkv);

  // kv / ksum: partial reduce -> finalize (bf16, transposed, swizzled)
  kv_reduce<<<2048, tb, 0, stream>>>(qkv, kv_part, ksum_part);
  kv_finalize<<<256, tb, 0, stream>>>(kv_part, ksum_part, kvT_g, ksum_f);

  // attention apply via MFMA -> ao (hbuf)
  attn_apply_mfma<<<2048, tb, 0, stream>>>(qkv, kvT_g, ksum_f, hbuf);

  // O projection + residual -> src2 (fp32)   (M=32768, N=1024; gx=128)
  gemm256<EPI_RES><<<dim3(512), tb, 0, stream>>>(
      hbuf, 1024, woT, 1024, 1024, 128, nullptr, src, src2);

  // LN2: src2 -> h2 (bf16, reuse hbuf)
  ln_kernel<<<32768, tb, 0, stream>>>(src2, ln2_w, ln2_b, hbuf);

  // MLP, 2 chunks of 16384 rows (a1c aliases dead qkv buffer)
  for (int c = 0; c < 2; c++) {
    const size_t mo = (size_t)c * 16384;
    // FC1: M=16384, N=4096, K=1024; gx=64
    gemm256<EPI_GELU><<<dim3(1024), tb, 0, stream>>>(
        hbuf + mo * 1024, 1024, fc1T, 1024, 4096, 64, fc1_b, nullptr, a1c);
    // FC2: M=16384, N=1024, K=4096; gx=64
    gemm256<EPI_FC2><<<dim3(256), tb, 0, stream>>>(
        a1c, 4096, fc2T, 4096, 1024, 64, fc2_b, src2 + mo * 1024,
        (float*)d_out + mo * 1024);
  }
}

// Round 11
// 1154.204 us; speedup vs baseline: 1.6506x; 1.6506x over previous
//
#include <hip/hip_runtime.h>
#include <hip/hip_bf16.h>

// ---------- types ----------
typedef __attribute__((ext_vector_type(8))) short s16x8;
typedef __attribute__((ext_vector_type(4))) short s16x4;
typedef __attribute__((ext_vector_type(8))) __bf16 bf16x8;
typedef __attribute__((ext_vector_type(4))) float f32x4;

__device__ __forceinline__ float b2f(short s) {
  union { float f; unsigned u; } x;
  x.u = ((unsigned)(unsigned short)s) << 16;
  return x.f;
}
__device__ __forceinline__ short f2b(float f) {
  union { float f; unsigned u; } x;
  x.f = f;
  unsigned r = x.u + 0x7fff + ((x.u >> 16) & 1);  // RNE
  return (short)(r >> 16);
}
__device__ __forceinline__ bf16x8 asbf(s16x8 v) {
  union { s16x8 s; bf16x8 b; } u; u.s = v; return u.b;
}

#define GLD16(g, l) __builtin_amdgcn_global_load_lds( \
    (const __attribute__((address_space(1))) void*)(g), \
    (__attribute__((address_space(3))) void*)(l), 16, 0, 0)

#define WAITB(N) do { \
  asm volatile("s_waitcnt vmcnt(" #N ")" ::: "memory"); \
  __builtin_amdgcn_s_barrier(); \
  asm volatile("" ::: "memory"); \
} while (0)

// ---------- weight transpose + fp32->bf16 : out[c][r] = in[r][c] ----------
__global__ __launch_bounds__(256) void transpose_cvt(
    const float* __restrict__ in, short* __restrict__ out, int R, int C) {
  __shared__ float tile[32][33];
  const int tx = threadIdx.x & 31, ty = threadIdx.x >> 5;  // 32x8
  const int c0 = blockIdx.x * 32, r0 = blockIdx.y * 32;
  #pragma unroll
  for (int i = 0; i < 32; i += 8)
    tile[ty + i][tx] = in[(size_t)(r0 + ty + i) * C + c0 + tx];
  __syncthreads();
  #pragma unroll
  for (int i = 0; i < 32; i += 8)
    out[(size_t)(c0 + ty + i) * R + r0 + tx] = f2b(tile[tx][ty + i]);
}

// ---------- layernorm: fp32 [rows][1024] -> bf16 ----------
__global__ __launch_bounds__(256) void ln_kernel(
    const float* __restrict__ x, const float* __restrict__ gw,
    const float* __restrict__ gb, short* __restrict__ out) {
  const int row = blockIdx.x;
  const int tid = threadIdx.x;
  const float4 v = ((const float4*)(x + (size_t)row * 1024))[tid];
  float s = v.x + v.y + v.z + v.w;
  float s2 = v.x * v.x + v.y * v.y + v.z * v.z + v.w * v.w;
  #pragma unroll
  for (int o = 32; o > 0; o >>= 1) {
    s += __shfl_xor(s, o);
    s2 += __shfl_xor(s2, o);
  }
  __shared__ float red[2][4];
  const int lane = tid & 63, wid = tid >> 6;
  if (lane == 0) { red[0][wid] = s; red[1][wid] = s2; }
  __syncthreads();
  s = red[0][0] + red[0][1] + red[0][2] + red[0][3];
  s2 = red[1][0] + red[1][1] + red[1][2] + red[1][3];
  const float mu = s * (1.f / 1024.f);
  const float rstd = rsqrtf(s2 * (1.f / 1024.f) - mu * mu + 1e-5f);
  const float4 wv4 = ((const float4*)gw)[tid];
  const float4 bv4 = ((const float4*)gb)[tid];
  s16x4 o4;
  o4.x = f2b((v.x - mu) * rstd * wv4.x + bv4.x);
  o4.y = f2b((v.y - mu) * rstd * wv4.y + bv4.y);
  o4.z = f2b((v.z - mu) * rstd * wv4.z + bv4.z);
  o4.w = f2b((v.w - mu) * rstd * wv4.w + bv4.w);
  *(s16x4*)(out + (size_t)row * 1024 + tid * 4) = o4;
}

// ---------- 256x256 bf16 MFMA GEMM (r3-proven loop) + L2 super-tile mapping ----------
// C[M][N] = A[M][K] * Bt[N][K]^T, 512 thr = 8 waves (2Mx4N), BK=64, LDS 128KB.
// Loop/swizzle/staging byte-identical to r3 (228us best, 5-variant ledger).
// NEW (r10 conclusion): bid -> (bm,bn) via 32-block super-tiles of 8bm x 4bn,
// so each XCD's ~32 co-resident blocks share 8 A-panels (4MB) + 4 B-panels
// (2MB) ~ L2-resident, instead of bm-fast's 64MB A working set (L3-latency
// staging was the residual 35% wait). Requires gx%8==0 && gy%4==0 (all
// launches: 128x12, 128x4, 64x16, 64x4). Bijective: grp=bid>>5,
// sm=grp%(gx/8), sn=grp/(gx/8), bm=sm*8+(bid&7), bn=sn*4+((bid&31)>>3).

enum { EPI_QKV = 0, EPI_RES = 1, EPI_GELU = 2, EPI_FC2 = 3 };

#define PHASE(BUFB, MH, KS, LOADB) do { \
    const int ab = (BUFB) + (KS) * 16384; \
    const int bb = (BUFB) + 32768 + (KS) * 16384; \
    if (LOADB) { \
      _Pragma("unroll") \
      for (int n = 0; n < 4; n++) { \
        const int row = wnCol + n * 16 + fr; \
        const int g = row >> 1; \
        const int s = (((row & 1) << 2) | fq) ^ (g & 7); \
        bfv[n] = *(const bf16x8*)(ldsc + bb + g * 128 + s * 16); \
      } \
    } \
    bf16x8 af[4]; \
    _Pragma("unroll") \
    for (int mm = 0; mm < 4; mm++) { \
      const int row = wmRow + (MH) * 64 + mm * 16 + fr; \
      const int g = row >> 1; \
      const int s = (((row & 1) << 2) | fq) ^ (g & 7); \
      af[mm] = *(const bf16x8*)(ldsc + ab + g * 128 + s * 16); \
    } \
    __builtin_amdgcn_s_setprio(1); \
    _Pragma("unroll") \
    for (int mm = 0; mm < 4; mm++) \
      _Pragma("unroll") \
      for (int n = 0; n < 4; n++) \
        acc[(MH) * 4 + mm][n] = __builtin_amdgcn_mfma_f32_16x16x32_bf16( \
            af[mm], bfv[n], acc[(MH) * 4 + mm][n], 0, 0, 0); \
    __builtin_amdgcn_s_setprio(0); \
  } while (0)

template <int EPI>
__global__ __launch_bounds__(512, 2) void gemm256(
    const short* __restrict__ A, int lda,
    const short* __restrict__ Bt, int K, int ldo, int gx,
    const float* __restrict__ bias,
    const float* __restrict__ resid,
    void* __restrict__ outp) {
  __shared__ alignas(16) short lds[65536];  // 128 KiB
  const int tid = threadIdx.x;
  const int lane = tid & 63, wave = tid >> 6;
  // T1: bijective XCD swizzle (grid % 8 == 0 for all launches)
  const int cpx = (int)gridDim.x >> 3;
  const int bid = ((int)blockIdx.x & 7) * cpx + ((int)blockIdx.x >> 3);
  // L2 super-tile mapping: 32-block groups of 8bm x 4bn
  const int sgx = gx >> 3;
  const int grp = bid >> 5;
  const int sm = grp % sgx, sn = grp / sgx;
  const int bm = (sm * 8 + (bid & 7)) * 256;
  const int bn = (sn * 4 + ((bid & 31) >> 3)) * 256;
  const int wmRow = (wave >> 2) * 128;
  const int wnCol = (wave & 3) * 64;
  const int fr = lane & 15, fq = lane >> 4;

  // staging constants: inverse-swizzled global source, linear LDS dest
  const int sg = tid >> 3;
  const int s0 = (tid & 7) ^ (sg & 7);
  const int srow = 2 * sg + (s0 >> 2);   // load 0 row; load 1 adds 128
  const int scol = (s0 & 3) * 8;
  const int sdst = tid * 16;

  const char* ldsc = (const char*)lds;
  char* ldsw = (char*)lds;

  f32x4 acc[8][4] = {};
  bf16x8 bfv[4];

  auto stageA = [&](int bufb, int kh, int kk) {
    const short* g = A + (size_t)(bm + srow) * lda + kk + kh * 32 + scol;
    char* l = ldsw + bufb + kh * 16384 + sdst;
    GLD16(g, l);
    GLD16(g + (size_t)128 * lda, l + 8192);
  };
  auto stageB = [&](int bufb, int kh, int kk) {
    const short* g = Bt + (size_t)(bn + srow) * K + kk + kh * 32 + scol;
    char* l = ldsw + bufb + 32768 + kh * 16384 + sdst;
    GLD16(g, l);
    GLD16(g + (size_t)128 * K, l + 8192);
  };

  const int NT = K >> 6;
  // prologue: full tile 0 into buf0; WAITB(4) -> kh0 proven, kh1 in flight
  stageA(0, 0, 0);
  stageB(0, 0, 0);
  stageA(0, 1, 0);
  stageB(0, 1, 0);
  WAITB(4);

  int buf = 0;
  for (int t = 0; t < NT; ++t) {
    const int kkn = (t + 1 < NT) ? ((t + 1) << 6) : 0;  // clamp keeps counts uniform
    const int nb = buf ^ 65536;
    stageA(nb, 0, kkn);
    PHASE(buf, 0, 0, true);
    stageB(nb, 0, kkn);
    PHASE(buf, 1, 0, false);
    WAITB(8);                       // kh1(t) proven; in-flight = kh0(t+1)... (r3 ledger)
    stageA(nb, 1, kkn);
    PHASE(buf, 0, 1, true);
    stageB(nb, 1, kkn);
    PHASE(buf, 1, 1, false);
    WAITB(4);                       // kh0(t+1) proven; in-flight = kh1(t+1)
    buf = nb;
  }
  asm volatile("s_waitcnt vmcnt(0)" ::: "memory");

  // epilogue: row = bm+wmRow+m*16+fq*4+r ; col = bn+wnCol+n*16+fr
  const int row0 = bm + wmRow + fq * 4;
  const int col0 = bn + wnCol + fr;
  #pragma unroll
  for (int m = 0; m < 8; m++) {
    #pragma unroll
    for (int n = 0; n < 4; n++) {
      const int col = col0 + n * 16;
      #pragma unroll
      for (int r = 0; r < 4; r++) {
        const int row = row0 + m * 16 + r;
        float v = acc[m][n][r];
        if constexpr (EPI == EPI_QKV) {
          if (col < 2048) v = (v > 0.f) ? (v + 1.f) : __expf(v);  // phi = elu+1
          ((short*)outp)[(size_t)row * ldo + col] = f2b(v);
        } else if constexpr (EPI == EPI_RES) {
          ((float*)outp)[(size_t)row * ldo + col] =
              v + resid[(size_t)row * ldo + col];
        } else if constexpr (EPI == EPI_GELU) {
          v += bias[col];
          v = 0.5f * v * (1.f + erff(v * 0.70710678118654752f));
          ((short*)outp)[(size_t)row * ldo + col] = f2b(v);
        } else {  // EPI_FC2
          v += bias[col] + resid[(size_t)row * ldo + col];
          ((float*)outp)[(size_t)row * ldo + col] = v;
        }
      }
    }
  }
}

// ---------- kv partial reduce: per (b,h,chunk) 64x64 outer-product partial ----------
// grid 2048 = 64 bh * 32 chunks of 256 rows
__global__ __launch_bounds__(256) void kv_reduce(
    const short* __restrict__ qkv, float* __restrict__ kv_part,
    float* __restrict__ ksum_part) {
  const int blk = blockIdx.x;
  const int bh = blk >> 5, chunk = blk & 31;
  const int b = bh >> 4, h = bh & 15;
  const size_t rowbase = (size_t)b * 8192 + (size_t)chunk * 256;
  const int kcol = 1024 + h * 64, vcol = 2048 + h * 64;
  __shared__ short Kl[64][64];
  __shared__ short Vl[64][64];
  const int tid = threadIdx.x;
  const int dk = tid >> 2, dq = tid & 3;
  float acc[16] = {};
  float ks = 0.f;
  for (int t = 0; t < 4; t++) {
    #pragma unroll
    for (int i = 0; i < 2; i++) {
      const int s = i * 256 + tid;
      const int r = s >> 3, seg = (s & 7) * 8;
      const size_t g = (rowbase + t * 64 + r) * 3072;
      *(s16x8*)&Kl[r][seg] = *(const s16x8*)&qkv[g + kcol + seg];
      *(s16x8*)&Vl[r][seg] = *(const s16x8*)&qkv[g + vcol + seg];
    }
    __syncthreads();
    for (int n = 0; n < 64; n++) {
      const float kval = b2f(Kl[n][dk]);
      if (dq == 0) ks += kval;
      const s16x8 v0 = *(const s16x8*)&Vl[n][dq * 16];
      const s16x8 v1 = *(const s16x8*)&Vl[n][dq * 16 + 8];
      #pragma unroll
      for (int j = 0; j < 8; j++) {
        acc[j] = fmaf(kval, b2f(v0[j]), acc[j]);
        acc[8 + j] = fmaf(kval, b2f(v1[j]), acc[8 + j]);
      }
    }
    __syncthreads();
  }
  float* dst = kv_part + (size_t)blk * 4096 + dk * 64 + dq * 16;
  #pragma unroll
  for (int j = 0; j < 16; j++) dst[j] = acc[j];
  if (dq == 0) ksum_part[(size_t)blk * 64 + dk] = ks;
}

// ---------- kv finalize: reduce 32 partials -> bf16 kv^T, pre-swizzled ----------
__global__ __launch_bounds__(256) void kv_finalize(
    const float* __restrict__ kv_part, const float* __restrict__ ksum_part,
    short* __restrict__ kvT_g, float* __restrict__ ksum_f) {
  const int bh = blockIdx.x >> 2, dg = blockIdx.x & 3;
  const int tid = threadIdx.x;
  const int e = tid & 63, j4 = tid >> 6;
  const int d0 = dg * 16 + j4 * 4;
  float a0 = 0.f, a1 = 0.f, a2 = 0.f, a3 = 0.f;
  const float* base = kv_part + (size_t)bh * 32 * 4096 + d0 * 64 + e;
  for (int c = 0; c < 32; c++) {
    const float* p = base + (size_t)c * 4096;
    a0 += p[0]; a1 += p[64]; a2 += p[128]; a3 += p[192];
  }
  s16x4 o; o.x = f2b(a0); o.y = f2b(a1); o.z = f2b(a2); o.w = f2b(a3);
  char* dstb = (char*)(kvT_g + (size_t)bh * 4096);
  *(s16x4*)(dstb + e * 128 + ((2 * d0) ^ ((e & 7) << 4))) = o;
  if (tid < 16) {
    const int d = dg * 16 + tid;
    float s = 0.f;
    for (int c = 0; c < 32; c++)
      s += ksum_part[((size_t)bh * 32 + c) * 64 + d];
    ksum_f[bh * 64 + d] = s;
  }
}

// ---------- attention apply via MFMA: ao = (Q @ kv) / (Q . ksum + eps) ----------
__global__ __launch_bounds__(256) void attn_apply_mfma(
    const short* __restrict__ qkv, const short* __restrict__ kvT_g,
    const float* __restrict__ ksum_f, short* __restrict__ ao) {
  __shared__ alignas(16) short kvs[4096];
  __shared__ float ksl[64];
  const int blk = blockIdx.x;
  const int bh = blk >> 5, rc = blk & 31;
  const int b = bh >> 4, h = bh & 15;
  const int tid = threadIdx.x, lane = tid & 63, w = tid >> 6;
  const int fr = lane & 15, fq = lane >> 4;

  GLD16(kvT_g + (size_t)bh * 4096 + tid * 8, (char*)kvs + tid * 16);
  GLD16(kvT_g + (size_t)bh * 4096 + (256 + tid) * 8, (char*)kvs + (256 + tid) * 16);
  if (tid < 64) ksl[tid] = ksum_f[bh * 64 + tid];
  __syncthreads();

  bf16x8 bkv[4][2], bns[2];
  #pragma unroll
  for (int n = 0; n < 4; n++) {
    #pragma unroll
    for (int c = 0; c < 2; c++) {
      const int e = n * 16 + fr;
      const int byteoff = e * 128 + ((c * 64 + fq * 16) ^ ((e & 7) << 4));
      bkv[n][c] = *(const bf16x8*)((const char*)kvs + byteoff);
    }
  }
  #pragma unroll
  for (int c = 0; c < 2; c++) {
    s16x8 ts = {0, 0, 0, 0, 0, 0, 0, 0};
    if (fr == 0) {
      #pragma unroll
      for (int j = 0; j < 8; j++) ts[j] = f2b(ksl[c * 32 + fq * 8 + j]);
    }
    bns[c] = asbf(ts);
  }

  f32x4 acc[4][4] = {};
  f32x4 nacc[4] = {};
  const size_t rowbase = (size_t)b * 8192 + (size_t)rc * 256 + w * 64;
  const int qcol = h * 64;
  #pragma unroll
  for (int m = 0; m < 4; m++) {
    const short* qrow = qkv + (rowbase + m * 16 + fr) * 3072 + qcol + fq * 8;
    const bf16x8 a0 = *(const bf16x8*)qrow;
    const bf16x8 a1 = *(const bf16x8*)(qrow + 32);
    #pragma unroll
    for (int n = 0; n < 4; n++) {
      acc[m][n] = __builtin_amdgcn_mfma_f32_16x16x32_bf16(a0, bkv[n][0], acc[m][n], 0, 0, 0);
      acc[m][n] = __builtin_amdgcn_mfma_f32_16x16x32_bf16(a1, bkv[n][1], acc[m][n], 0, 0, 0);
    }
    nacc[m] = __builtin_amdgcn_mfma_f32_16x16x32_bf16(a0, bns[0], nacc[m], 0, 0, 0);
    nacc[m] = __builtin_amdgcn_mfma_f32_16x16x32_bf16(a1, bns[1], nacc[m], 0, 0, 0);
  }

  #pragma unroll
  for (int m = 0; m < 4; m++) {
    #pragma unroll
    for (int r = 0; r < 4; r++) {
      const float nv = __shfl(nacc[m][r], lane & 48) + 1e-6f;
      const float rn = 1.f / nv;
      const size_t row = rowbase + m * 16 + fq * 4 + r;
      #pragma unroll
      for (int n = 0; n < 4; n++)
        ao[row * 1024 + qcol + n * 16 + fr] = f2b(acc[m][n][r] * rn);
    }
  }
}

// ---------- launcher ----------
extern "C" void kernel_launch(void* const* d_in, const int* in_sizes, int n_in,
                              void* d_out, int out_size, void* d_ws, size_t ws_size,
                              hipStream_t stream) {
  (void)in_sizes; (void)n_in; (void)out_size; (void)ws_size;
  const float* src   = (const float*)d_in[0];
  const float* ln1_w = (const float*)d_in[1];
  const float* ln1_b = (const float*)d_in[2];
  const float* wq    = (const float*)d_in[3];
  const float* wk    = (const float*)d_in[4];
  const float* wv    = (const float*)d_in[5];
  const float* wo    = (const float*)d_in[6];
  const float* ln2_w = (const float*)d_in[7];
  const float* ln2_b = (const float*)d_in[8];
  const float* fc1_w = (const float*)d_in[9];
  const float* fc1_b = (const float*)d_in[10];
  const float* fc2_w = (const float*)d_in[11];
  const float* fc2_b = (const float*)d_in[12];

  char* ws = (char*)d_ws;
  short* wqkvT     = (short*)(ws + 0);            // [3072][1024] bf16
  short* woT       = (short*)(ws + 6291456);      // [1024][1024]
  short* fc1T      = (short*)(ws + 8388608);      // [4096][1024]
  short* fc2T      = (short*)(ws + 16777216);     // [1024][4096]
  short* kvT_g     = (short*)(ws + 25165824);     // [64][4096] bf16 swizzled
  float* ksum_f    = (float*)(ws + 25690112);     // [64][64]
  float* kv_part   = (float*)(ws + 25706496);     // [2048][4096] fp32
  float* ksum_part = (float*)(ws + 59260928);     // [2048][64]
  short* hbuf      = (short*)(ws + 59785216);     // [32768][1024] bf16 (h / ao / h2)
  float* src2      = (float*)(ws + 126894080);    // [32768][1024] fp32
  short* qkv       = (short*)(ws + 261111808);    // [32768][3072] bf16
  short* a1c       = (short*)(ws + 261111808);    // [16384][4096] bf16 (aliases qkv)
  // high-water: 462,438,400 bytes (< 503,447,552 proven in round 1)

  const dim3 tb(256);
  const dim3 tb512(512);

  // weights -> bf16 transposed
  transpose_cvt<<<dim3(32, 32), tb, 0, stream>>>(wq, wqkvT, 1024, 1024);
  transpose_cvt<<<dim3(32, 32), tb, 0, stream>>>(wk, wqkvT + 1024 * 1024, 1024, 1024);
  transpose_cvt<<<dim3(32, 32), tb, 0, stream>>>(wv, wqkvT + 2048 * 1024, 1024, 1024);
  transpose_cvt<<<dim3(32, 32), tb, 0, stream>>>(wo, woT, 1024, 1024);
  transpose_cvt<<<dim3(128, 32), tb, 0, stream>>>(fc1_w, fc1T, 1024, 4096);
  transpose_cvt<<<dim3(32, 128), tb, 0, stream>>>(fc2_w, fc2T, 4096, 1024);

  // LN1: src -> h (bf16)
  ln_kernel<<<32768, tb, 0, stream>>>(src, ln1_w, ln1_b, hbuf);

  // QKV projection + phi on Q,K   (M=32768, N=3072, K=1024; gx=128, gy=12)
  gemm256<EPI_QKV><<<dim3(1536), tb512, 0, stream>>>(
      hbuf, 1024, wqkvT, 1024, 3072, 128, nullptr, nullptr, qkv);

  // kv / ksum: partial reduce -> finalize (bf16, transposed, swizzled)
  kv_reduce<<<2048, tb, 0, stream>>>(qkv, kv_part, ksum_part);
  kv_finalize<<<256, tb, 0, stream>>>(kv_part, ksum_part, kvT_g, ksum_f);

  // attention apply via MFMA -> ao (hbuf)
  attn_apply_mfma<<<2048, tb, 0, stream>>>(qkv, kvT_g, ksum_f, hbuf);

  // O projection + residual -> src2 (fp32)   (M=32768, N=1024; gx=128, gy=4)
  gemm256<EPI_RES><<<dim3(512), tb512, 0, stream>>>(
      hbuf, 1024, woT, 1024, 1024, 128, nullptr, src, src2);

  // LN2: src2 -> h2 (bf16, reuse hbuf)
  ln_kernel<<<32768, tb, 0, stream>>>(src2, ln2_w, ln2_b, hbuf);

  // MLP, 2 chunks of 16384 rows (a1c aliases dead qkv buffer)
  for (int c = 0; c < 2; c++) {
    const size_t mo = (size_t)c * 16384;
    // FC1: M=16384, N=4096, K=1024; gx=64, gy=16
    gemm256<EPI_GELU><<<dim3(1024), tb512, 0, stream>>>(
        hbuf + mo * 1024, 1024, fc1T, 1024, 4096, 64, fc1_b, nullptr, a1c);
    // FC2: M=16384, N=1024, K=4096; gx=64, gy=4
    gemm256<EPI_FC2><<<dim3(256), tb512, 0, stream>>>(
        a1c, 4096, fc2T, 4096, 1024, 64, fc2_b, src2 + mo * 1024,
        (float*)d_out + mo * 1024);
  }
}

// Round 12
// 1140.472 us; speedup vs baseline: 1.6704x; 1.0120x over previous
//
#include <hip/hip_runtime.h>
#include <hip/hip_bf16.h>

// ---------- types ----------
typedef __attribute__((ext_vector_type(8))) short s16x8;
typedef __attribute__((ext_vector_type(4))) short s16x4;
typedef __attribute__((ext_vector_type(8))) __bf16 bf16x8;
typedef __attribute__((ext_vector_type(4))) float f32x4;

__device__ __forceinline__ float b2f(short s) {
  union { float f; unsigned u; } x;
  x.u = ((unsigned)(unsigned short)s) << 16;
  return x.f;
}
__device__ __forceinline__ short f2b(float f) {
  union { float f; unsigned u; } x;
  x.f = f;
  unsigned r = x.u + 0x7fff + ((x.u >> 16) & 1);  // RNE
  return (short)(r >> 16);
}
__device__ __forceinline__ bf16x8 asbf(s16x8 v) {
  union { s16x8 s; bf16x8 b; } u; u.s = v; return u.b;
}

#define GLD16(g, l) __builtin_amdgcn_global_load_lds( \
    (const __attribute__((address_space(1))) void*)(g), \
    (__attribute__((address_space(3))) void*)(l), 16, 0, 0)

#define WAITB(N) do { \
  asm volatile("s_waitcnt vmcnt(" #N ")" ::: "memory"); \
  __builtin_amdgcn_s_barrier(); \
  asm volatile("" ::: "memory"); \
} while (0)

// ---------- weight transpose + fp32->bf16 : out[c][r] = in[r][c] ----------
__global__ __launch_bounds__(256) void transpose_cvt(
    const float* __restrict__ in, short* __restrict__ out, int R, int C) {
  __shared__ float tile[32][33];
  const int tx = threadIdx.x & 31, ty = threadIdx.x >> 5;  // 32x8
  const int c0 = blockIdx.x * 32, r0 = blockIdx.y * 32;
  #pragma unroll
  for (int i = 0; i < 32; i += 8)
    tile[ty + i][tx] = in[(size_t)(r0 + ty + i) * C + c0 + tx];
  __syncthreads();
  #pragma unroll
  for (int i = 0; i < 32; i += 8)
    out[(size_t)(c0 + ty + i) * R + r0 + tx] = f2b(tile[tx][ty + i]);
}

// ---------- layernorm: fp32 [rows][1024] -> bf16 ----------
__global__ __launch_bounds__(256) void ln_kernel(
    const float* __restrict__ x, const float* __restrict__ gw,
    const float* __restrict__ gb, short* __restrict__ out) {
  const int row = blockIdx.x;
  const int tid = threadIdx.x;
  const float4 v = ((const float4*)(x + (size_t)row * 1024))[tid];
  float s = v.x + v.y + v.z + v.w;
  float s2 = v.x * v.x + v.y * v.y + v.z * v.z + v.w * v.w;
  #pragma unroll
  for (int o = 32; o > 0; o >>= 1) {
    s += __shfl_xor(s, o);
    s2 += __shfl_xor(s2, o);
  }
  __shared__ float red[2][4];
  const int lane = tid & 63, wid = tid >> 6;
  if (lane == 0) { red[0][wid] = s; red[1][wid] = s2; }
  __syncthreads();
  s = red[0][0] + red[0][1] + red[0][2] + red[0][3];
  s2 = red[1][0] + red[1][1] + red[1][2] + red[1][3];
  const float mu = s * (1.f / 1024.f);
  const float rstd = rsqrtf(s2 * (1.f / 1024.f) - mu * mu + 1e-5f);
  const float4 wv4 = ((const float4*)gw)[tid];
  const float4 bv4 = ((const float4*)gb)[tid];
  s16x4 o4;
  o4.x = f2b((v.x - mu) * rstd * wv4.x + bv4.x);
  o4.y = f2b((v.y - mu) * rstd * wv4.y + bv4.y);
  o4.z = f2b((v.z - mu) * rstd * wv4.z + bv4.z);
  o4.w = f2b((v.w - mu) * rstd * wv4.w + bv4.w);
  *(s16x4*)(out + (size_t)row * 1024 + tid * 4) = o4;
}

// ---------- 256x256 bf16 MFMA GEMM (r3-proven loop) + L2 super-tile mapping ----------
// Byte-identical to r11 (best: QKV 215us, MfmaUtil 43%, FETCH 156MB, confl 0).
// 7 schedule/occupancy variants exhausted; mapping was the last real lever.

enum { EPI_QKV = 0, EPI_RES = 1, EPI_GELU = 2, EPI_FC2 = 3 };

#define PHASE(BUFB, MH, KS, LOADB) do { \
    const int ab = (BUFB) + (KS) * 16384; \
    const int bb = (BUFB) + 32768 + (KS) * 16384; \
    if (LOADB) { \
      _Pragma("unroll") \
      for (int n = 0; n < 4; n++) { \
        const int row = wnCol + n * 16 + fr; \
        const int g = row >> 1; \
        const int s = (((row & 1) << 2) | fq) ^ (g & 7); \
        bfv[n] = *(const bf16x8*)(ldsc + bb + g * 128 + s * 16); \
      } \
    } \
    bf16x8 af[4]; \
    _Pragma("unroll") \
    for (int mm = 0; mm < 4; mm++) { \
      const int row = wmRow + (MH) * 64 + mm * 16 + fr; \
      const int g = row >> 1; \
      const int s = (((row & 1) << 2) | fq) ^ (g & 7); \
      af[mm] = *(const bf16x8*)(ldsc + ab + g * 128 + s * 16); \
    } \
    __builtin_amdgcn_s_setprio(1); \
    _Pragma("unroll") \
    for (int mm = 0; mm < 4; mm++) \
      _Pragma("unroll") \
      for (int n = 0; n < 4; n++) \
        acc[(MH) * 4 + mm][n] = __builtin_amdgcn_mfma_f32_16x16x32_bf16( \
            af[mm], bfv[n], acc[(MH) * 4 + mm][n], 0, 0, 0); \
    __builtin_amdgcn_s_setprio(0); \
  } while (0)

template <int EPI>
__global__ __launch_bounds__(512, 2) void gemm256(
    const short* __restrict__ A, int lda,
    const short* __restrict__ Bt, int K, int ldo, int gx,
    const float* __restrict__ bias,
    const float* __restrict__ resid,
    void* __restrict__ outp) {
  __shared__ alignas(16) short lds[65536];  // 128 KiB
  const int tid = threadIdx.x;
  const int lane = tid & 63, wave = tid >> 6;
  // T1: bijective XCD swizzle (grid % 8 == 0 for all launches)
  const int cpx = (int)gridDim.x >> 3;
  const int bid = ((int)blockIdx.x & 7) * cpx + ((int)blockIdx.x >> 3);
  // L2 super-tile mapping: 32-block groups of 8bm x 4bn
  const int sgx = gx >> 3;
  const int grp = bid >> 5;
  const int sm = grp % sgx, sn = grp / sgx;
  const int bm = (sm * 8 + (bid & 7)) * 256;
  const int bn = (sn * 4 + ((bid & 31) >> 3)) * 256;
  const int wmRow = (wave >> 2) * 128;
  const int wnCol = (wave & 3) * 64;
  const int fr = lane & 15, fq = lane >> 4;

  // staging constants: inverse-swizzled global source, linear LDS dest
  const int sg = tid >> 3;
  const int s0 = (tid & 7) ^ (sg & 7);
  const int srow = 2 * sg + (s0 >> 2);   // load 0 row; load 1 adds 128
  const int scol = (s0 & 3) * 8;
  const int sdst = tid * 16;

  const char* ldsc = (const char*)lds;
  char* ldsw = (char*)lds;

  f32x4 acc[8][4] = {};
  bf16x8 bfv[4];

  auto stageA = [&](int bufb, int kh, int kk) {
    const short* g = A + (size_t)(bm + srow) * lda + kk + kh * 32 + scol;
    char* l = ldsw + bufb + kh * 16384 + sdst;
    GLD16(g, l);
    GLD16(g + (size_t)128 * lda, l + 8192);
  };
  auto stageB = [&](int bufb, int kh, int kk) {
    const short* g = Bt + (size_t)(bn + srow) * K + kk + kh * 32 + scol;
    char* l = ldsw + bufb + 32768 + kh * 16384 + sdst;
    GLD16(g, l);
    GLD16(g + (size_t)128 * K, l + 8192);
  };

  const int NT = K >> 6;
  // prologue: full tile 0 into buf0; WAITB(4) -> kh0 proven, kh1 in flight
  stageA(0, 0, 0);
  stageB(0, 0, 0);
  stageA(0, 1, 0);
  stageB(0, 1, 0);
  WAITB(4);

  int buf = 0;
  for (int t = 0; t < NT; ++t) {
    const int kkn = (t + 1 < NT) ? ((t + 1) << 6) : 0;  // clamp keeps counts uniform
    const int nb = buf ^ 65536;
    stageA(nb, 0, kkn);
    PHASE(buf, 0, 0, true);
    stageB(nb, 0, kkn);
    PHASE(buf, 1, 0, false);
    WAITB(8);                       // kh1(t) proven (r3 ledger)
    stageA(nb, 1, kkn);
    PHASE(buf, 0, 1, true);
    stageB(nb, 1, kkn);
    PHASE(buf, 1, 1, false);
    WAITB(4);                       // kh0(t+1) proven; in-flight = kh1(t+1)
    buf = nb;
  }
  asm volatile("s_waitcnt vmcnt(0)" ::: "memory");

  // epilogue: row = bm+wmRow+m*16+fq*4+r ; col = bn+wnCol+n*16+fr
  const int row0 = bm + wmRow + fq * 4;
  const int col0 = bn + wnCol + fr;
  #pragma unroll
  for (int m = 0; m < 8; m++) {
    #pragma unroll
    for (int n = 0; n < 4; n++) {
      const int col = col0 + n * 16;
      #pragma unroll
      for (int r = 0; r < 4; r++) {
        const int row = row0 + m * 16 + r;
        float v = acc[m][n][r];
        if constexpr (EPI == EPI_QKV) {
          if (col < 2048) v = (v > 0.f) ? (v + 1.f) : __expf(v);  // phi = elu+1
          ((short*)outp)[(size_t)row * ldo + col] = f2b(v);
        } else if constexpr (EPI == EPI_RES) {
          ((float*)outp)[(size_t)row * ldo + col] =
              v + resid[(size_t)row * ldo + col];
        } else if constexpr (EPI == EPI_GELU) {
          v += bias[col];
          v = 0.5f * v * (1.f + erff(v * 0.70710678118654752f));
          ((short*)outp)[(size_t)row * ldo + col] = f2b(v);
        } else {  // EPI_FC2
          v += bias[col] + resid[(size_t)row * ldo + col];
          ((float*)outp)[(size_t)row * ldo + col] = v;
        }
      }
    }
  }
}

// ---------- kv partial reduce v2: fp32 LDS tiles, 2x occupancy ----------
// r11 analysis: v1 was VALU-bound (~110us est): 16 redundant b2f per thread
// per n (each V elem converted 64x) at 2 waves/SIMD. v2: convert K/V tiles
// to fp32 in LDS ONCE (conversions /64), pad rows to 68 floats (bank-spread,
// float4-aligned), 4096 blocks of 128 rows -> 16 waves/CU, 4 blocks/CU.
__global__ __launch_bounds__(256) void kv_reduce(
    const short* __restrict__ qkv, float* __restrict__ kv_part,
    float* __restrict__ ksum_part) {
  const int blk = blockIdx.x;  // 4096 = 64 bh * 64 chunks
  const int bh = blk >> 6, chunk = blk & 63;
  const int b = bh >> 4, h = bh & 15;
  const size_t rowbase = (size_t)b * 8192 + (size_t)chunk * 128;
  const int kcol = 1024 + h * 64, vcol = 2048 + h * 64;
  __shared__ float Klf[64][68];
  __shared__ float Vlf[64][68];
  const int tid = threadIdx.x;
  const int dk = tid >> 2, dq = tid & 3;
  float acc[16] = {};
  float ks = 0.f;
  for (int t = 0; t < 2; t++) {
    #pragma unroll
    for (int i = 0; i < 2; i++) {
      const int s = i * 256 + tid;
      const int r = s >> 3, seg = (s & 7) * 8;
      const size_t g = (rowbase + t * 64 + r) * 3072;
      const s16x8 k8 = *(const s16x8*)&qkv[g + kcol + seg];
      const s16x8 v8 = *(const s16x8*)&qkv[g + vcol + seg];
      float4 ka, kb, va, vb;
      ka.x = b2f(k8[0]); ka.y = b2f(k8[1]); ka.z = b2f(k8[2]); ka.w = b2f(k8[3]);
      kb.x = b2f(k8[4]); kb.y = b2f(k8[5]); kb.z = b2f(k8[6]); kb.w = b2f(k8[7]);
      va.x = b2f(v8[0]); va.y = b2f(v8[1]); va.z = b2f(v8[2]); va.w = b2f(v8[3]);
      vb.x = b2f(v8[4]); vb.y = b2f(v8[5]); vb.z = b2f(v8[6]); vb.w = b2f(v8[7]);
      *(float4*)&Klf[r][seg] = ka;
      *(float4*)&Klf[r][seg + 4] = kb;
      *(float4*)&Vlf[r][seg] = va;
      *(float4*)&Vlf[r][seg + 4] = vb;
    }
    __syncthreads();
    #pragma unroll 4
    for (int n = 0; n < 64; n++) {
      const float kval = Klf[n][dk];
      if (dq == 0) ks += kval;
      const float4 v0 = *(const float4*)&Vlf[n][dq * 16];
      const float4 v1 = *(const float4*)&Vlf[n][dq * 16 + 4];
      const float4 v2 = *(const float4*)&Vlf[n][dq * 16 + 8];
      const float4 v3 = *(const float4*)&Vlf[n][dq * 16 + 12];
      acc[0]  = fmaf(kval, v0.x, acc[0]);
      acc[1]  = fmaf(kval, v0.y, acc[1]);
      acc[2]  = fmaf(kval, v0.z, acc[2]);
      acc[3]  = fmaf(kval, v0.w, acc[3]);
      acc[4]  = fmaf(kval, v1.x, acc[4]);
      acc[5]  = fmaf(kval, v1.y, acc[5]);
      acc[6]  = fmaf(kval, v1.z, acc[6]);
      acc[7]  = fmaf(kval, v1.w, acc[7]);
      acc[8]  = fmaf(kval, v2.x, acc[8]);
      acc[9]  = fmaf(kval, v2.y, acc[9]);
      acc[10] = fmaf(kval, v2.z, acc[10]);
      acc[11] = fmaf(kval, v2.w, acc[11]);
      acc[12] = fmaf(kval, v3.x, acc[12]);
      acc[13] = fmaf(kval, v3.y, acc[13]);
      acc[14] = fmaf(kval, v3.z, acc[14]);
      acc[15] = fmaf(kval, v3.w, acc[15]);
    }
    __syncthreads();
  }
  float* dst = kv_part + (size_t)blk * 4096 + dk * 64 + dq * 16;
  #pragma unroll
  for (int j = 0; j < 16; j++) dst[j] = acc[j];
  if (dq == 0) ksum_part[(size_t)blk * 64 + dk] = ks;
}

// ---------- kv finalize: reduce 64 partials -> bf16 kv^T, pre-swizzled ----------
__global__ __launch_bounds__(256) void kv_finalize(
    const float* __restrict__ kv_part, const float* __restrict__ ksum_part,
    short* __restrict__ kvT_g, float* __restrict__ ksum_f) {
  const int bh = blockIdx.x >> 2, dg = blockIdx.x & 3;
  const int tid = threadIdx.x;
  const int e = tid & 63, j4 = tid >> 6;
  const int d0 = dg * 16 + j4 * 4;
  float a0 = 0.f, a1 = 0.f, a2 = 0.f, a3 = 0.f;
  const float* base = kv_part + (size_t)bh * 64 * 4096 + d0 * 64 + e;
  for (int c = 0; c < 64; c++) {
    const float* p = base + (size_t)c * 4096;
    a0 += p[0]; a1 += p[64]; a2 += p[128]; a3 += p[192];
  }
  s16x4 o; o.x = f2b(a0); o.y = f2b(a1); o.z = f2b(a2); o.w = f2b(a3);
  char* dstb = (char*)(kvT_g + (size_t)bh * 4096);
  *(s16x4*)(dstb + e * 128 + ((2 * d0) ^ ((e & 7) << 4))) = o;
  if (tid < 16) {
    const int d = dg * 16 + tid;
    float s = 0.f;
    for (int c = 0; c < 64; c++)
      s += ksum_part[((size_t)bh * 64 + c) * 64 + d];
    ksum_f[bh * 64 + d] = s;
  }
}

// ---------- attention apply via MFMA: ao = (Q @ kv) / (Q . ksum + eps) ----------
__global__ __launch_bounds__(256) void attn_apply_mfma(
    const short* __restrict__ qkv, const short* __restrict__ kvT_g,
    const float* __restrict__ ksum_f, short* __restrict__ ao) {
  __shared__ alignas(16) short kvs[4096];
  __shared__ float ksl[64];
  const int blk = blockIdx.x;
  const int bh = blk >> 5, rc = blk & 31;
  const int b = bh >> 4, h = bh & 15;
  const int tid = threadIdx.x, lane = tid & 63, w = tid >> 6;
  const int fr = lane & 15, fq = lane >> 4;

  GLD16(kvT_g + (size_t)bh * 4096 + tid * 8, (char*)kvs + tid * 16);
  GLD16(kvT_g + (size_t)bh * 4096 + (256 + tid) * 8, (char*)kvs + (256 + tid) * 16);
  if (tid < 64) ksl[tid] = ksum_f[bh * 64 + tid];
  __syncthreads();

  bf16x8 bkv[4][2], bns[2];
  #pragma unroll
  for (int n = 0; n < 4; n++) {
    #pragma unroll
    for (int c = 0; c < 2; c++) {
      const int e = n * 16 + fr;
      const int byteoff = e * 128 + ((c * 64 + fq * 16) ^ ((e & 7) << 4));
      bkv[n][c] = *(const bf16x8*)((const char*)kvs + byteoff);
    }
  }
  #pragma unroll
  for (int c = 0; c < 2; c++) {
    s16x8 ts = {0, 0, 0, 0, 0, 0, 0, 0};
    if (fr == 0) {
      #pragma unroll
      for (int j = 0; j < 8; j++) ts[j] = f2b(ksl[c * 32 + fq * 8 + j]);
    }
    bns[c] = asbf(ts);
  }

  f32x4 acc[4][4] = {};
  f32x4 nacc[4] = {};
  const size_t rowbase = (size_t)b * 8192 + (size_t)rc * 256 + w * 64;
  const int qcol = h * 64;
  #pragma unroll
  for (int m = 0; m < 4; m++) {
    const short* qrow = qkv + (rowbase + m * 16 + fr) * 3072 + qcol + fq * 8;
    const bf16x8 a0 = *(const bf16x8*)qrow;
    const bf16x8 a1 = *(const bf16x8*)(qrow + 32);
    #pragma unroll
    for (int n = 0; n < 4; n++) {
      acc[m][n] = __builtin_amdgcn_mfma_f32_16x16x32_bf16(a0, bkv[n][0], acc[m][n], 0, 0, 0);
      acc[m][n] = __builtin_amdgcn_mfma_f32_16x16x32_bf16(a1, bkv[n][1], acc[m][n], 0, 0, 0);
    }
    nacc[m] = __builtin_amdgcn_mfma_f32_16x16x32_bf16(a0, bns[0], nacc[m], 0, 0, 0);
    nacc[m] = __builtin_amdgcn_mfma_f32_16x16x32_bf16(a1, bns[1], nacc[m], 0, 0, 0);
  }

  #pragma unroll
  for (int m = 0; m < 4; m++) {
    #pragma unroll
    for (int r = 0; r < 4; r++) {
      const float nv = __shfl(nacc[m][r], lane & 48) + 1e-6f;
      const float rn = 1.f / nv;
      const size_t row = rowbase + m * 16 + fq * 4 + r;
      #pragma unroll
      for (int n = 0; n < 4; n++)
        ao[row * 1024 + qcol + n * 16 + fr] = f2b(acc[m][n][r] * rn);
    }
  }
}

// ---------- launcher ----------
extern "C" void kernel_launch(void* const* d_in, const int* in_sizes, int n_in,
                              void* d_out, int out_size, void* d_ws, size_t ws_size,
                              hipStream_t stream) {
  (void)in_sizes; (void)n_in; (void)out_size; (void)ws_size;
  const float* src   = (const float*)d_in[0];
  const float* ln1_w = (const float*)d_in[1];
  const float* ln1_b = (const float*)d_in[2];
  const float* wq    = (const float*)d_in[3];
  const float* wk    = (const float*)d_in[4];
  const float* wv    = (const float*)d_in[5];
  const float* wo    = (const float*)d_in[6];
  const float* ln2_w = (const float*)d_in[7];
  const float* ln2_b = (const float*)d_in[8];
  const float* fc1_w = (const float*)d_in[9];
  const float* fc1_b = (const float*)d_in[10];
  const float* fc2_w = (const float*)d_in[11];
  const float* fc2_b = (const float*)d_in[12];

  char* ws = (char*)d_ws;
  short* wqkvT     = (short*)(ws + 0);            // [3072][1024] bf16
  short* woT       = (short*)(ws + 6291456);      // [1024][1024]
  short* fc1T      = (short*)(ws + 8388608);      // [4096][1024]
  short* fc2T      = (short*)(ws + 16777216);     // [1024][4096]
  short* kvT_g     = (short*)(ws + 25165824);     // [64][4096] bf16 swizzled
  float* ksum_f    = (float*)(ws + 25690112);     // [64][64]
  float* kv_part   = (float*)(ws + 25706496);     // [4096][4096] fp32 (67.1MB)
  float* ksum_part = (float*)(ws + 92815360);     // [4096][64]
  short* hbuf      = (short*)(ws + 93863936);     // [32768][1024] bf16 (h / ao / h2)
  float* src2      = (float*)(ws + 160972800);    // [32768][1024] fp32
  short* qkv       = (short*)(ws + 295190528);    // [32768][3072] bf16
  short* a1c       = (short*)(ws + 295190528);    // [16384][4096] bf16 (aliases qkv)
  // high-water: 496,517,120 bytes (< 503,447,552 proven in round 1)

  const dim3 tb(256);
  const dim3 tb512(512);

  // weights -> bf16 transposed
  transpose_cvt<<<dim3(32, 32), tb, 0, stream>>>(wq, wqkvT, 1024, 1024);
  transpose_cvt<<<dim3(32, 32), tb, 0, stream>>>(wk, wqkvT + 1024 * 1024, 1024, 1024);
  transpose_cvt<<<dim3(32, 32), tb, 0, stream>>>(wv, wqkvT + 2048 * 1024, 1024, 1024);
  transpose_cvt<<<dim3(32, 32), tb, 0, stream>>>(wo, woT, 1024, 1024);
  transpose_cvt<<<dim3(128, 32), tb, 0, stream>>>(fc1_w, fc1T, 1024, 4096);
  transpose_cvt<<<dim3(32, 128), tb, 0, stream>>>(fc2_w, fc2T, 4096, 1024);

  // LN1: src -> h (bf16)
  ln_kernel<<<32768, tb, 0, stream>>>(src, ln1_w, ln1_b, hbuf);

  // QKV projection + phi on Q,K   (M=32768, N=3072, K=1024; gx=128, gy=12)
  gemm256<EPI_QKV><<<dim3(1536), tb512, 0, stream>>>(
      hbuf, 1024, wqkvT, 1024, 3072, 128, nullptr, nullptr, qkv);

  // kv / ksum: partial reduce (v2) -> finalize (bf16, transposed, swizzled)
  kv_reduce<<<4096, tb, 0, stream>>>(qkv, kv_part, ksum_part);
  kv_finalize<<<256, tb, 0, stream>>>(kv_part, ksum_part, kvT_g, ksum_f);

  // attention apply via MFMA -> ao (hbuf)
  attn_apply_mfma<<<2048, tb, 0, stream>>>(qkv, kvT_g, ksum_f, hbuf);

  // O projection + residual -> src2 (fp32)   (M=32768, N=1024; gx=128, gy=4)
  gemm256<EPI_RES><<<dim3(512), tb512, 0, stream>>>(
      hbuf, 1024, woT, 1024, 1024, 128, nullptr, src, src2);

  // LN2: src2 -> h2 (bf16, reuse hbuf)
  ln_kernel<<<32768, tb, 0, stream>>>(src2, ln2_w, ln2_b, hbuf);

  // MLP, 2 chunks of 16384 rows (a1c aliases dead qkv buffer)
  for (int c = 0; c < 2; c++) {
    const size_t mo = (size_t)c * 16384;
    // FC1: M=16384, N=4096, K=1024; gx=64, gy=16
    gemm256<EPI_GELU><<<dim3(1024), tb512, 0, stream>>>(
        hbuf + mo * 1024, 1024, fc1T, 1024, 4096, 64, fc1_b, nullptr, a1c);
    // FC2: M=16384, N=1024, K=4096; gx=64, gy=4
    gemm256<EPI_FC2><<<dim3(256), tb512, 0, stream>>>(
        a1c, 4096, fc2T, 4096, 1024, 64, fc2_b, src2 + mo * 1024,
        (float*)d_out + mo * 1024);
  }
}

// Round 13
// 1128.277 us; speedup vs baseline: 1.6885x; 1.0108x over previous
//
#include <hip/hip_runtime.h>
#include <hip/hip_bf16.h>

// ---------- types ----------
typedef __attribute__((ext_vector_type(8))) short s16x8;
typedef __attribute__((ext_vector_type(4))) short s16x4;
typedef __attribute__((ext_vector_type(8))) __bf16 bf16x8;
typedef __attribute__((ext_vector_type(4))) float f32x4;

__device__ __forceinline__ float b2f(short s) {
  union { float f; unsigned u; } x;
  x.u = ((unsigned)(unsigned short)s) << 16;
  return x.f;
}
__device__ __forceinline__ short f2b(float f) {
  union { float f; unsigned u; } x;
  x.f = f;
  unsigned r = x.u + 0x7fff + ((x.u >> 16) & 1);  // RNE
  return (short)(r >> 16);
}
__device__ __forceinline__ bf16x8 asbf(s16x8 v) {
  union { s16x8 s; bf16x8 b; } u; u.s = v; return u.b;
}

#define GLD16(g, l) __builtin_amdgcn_global_load_lds( \
    (const __attribute__((address_space(1))) void*)(g), \
    (__attribute__((address_space(3))) void*)(l), 16, 0, 0)

#define WAITB(N) do { \
  asm volatile("s_waitcnt vmcnt(" #N ")" ::: "memory"); \
  __builtin_amdgcn_s_barrier(); \
  asm volatile("" ::: "memory"); \
} while (0)

// ---------- weight transpose + fp32->bf16 : out[c][r] = in[r][c] ----------
__global__ __launch_bounds__(256) void transpose_cvt(
    const float* __restrict__ in, short* __restrict__ out, int R, int C) {
  __shared__ float tile[32][33];
  const int tx = threadIdx.x & 31, ty = threadIdx.x >> 5;  // 32x8
  const int c0 = blockIdx.x * 32, r0 = blockIdx.y * 32;
  #pragma unroll
  for (int i = 0; i < 32; i += 8)
    tile[ty + i][tx] = in[(size_t)(r0 + ty + i) * C + c0 + tx];
  __syncthreads();
  #pragma unroll
  for (int i = 0; i < 32; i += 8)
    out[(size_t)(c0 + ty + i) * R + r0 + tx] = f2b(tile[tx][ty + i]);
}

// ---------- layernorm: fp32 [rows][1024] -> bf16 ----------
__global__ __launch_bounds__(256) void ln_kernel(
    const float* __restrict__ x, const float* __restrict__ gw,
    const float* __restrict__ gb, short* __restrict__ out) {
  const int row = blockIdx.x;
  const int tid = threadIdx.x;
  const float4 v = ((const float4*)(x + (size_t)row * 1024))[tid];
  float s = v.x + v.y + v.z + v.w;
  float s2 = v.x * v.x + v.y * v.y + v.z * v.z + v.w * v.w;
  #pragma unroll
  for (int o = 32; o > 0; o >>= 1) {
    s += __shfl_xor(s, o);
    s2 += __shfl_xor(s2, o);
  }
  __shared__ float red[2][4];
  const int lane = tid & 63, wid = tid >> 6;
  if (lane == 0) { red[0][wid] = s; red[1][wid] = s2; }
  __syncthreads();
  s = red[0][0] + red[0][1] + red[0][2] + red[0][3];
  s2 = red[1][0] + red[1][1] + red[1][2] + red[1][3];
  const float mu = s * (1.f / 1024.f);
  const float rstd = rsqrtf(s2 * (1.f / 1024.f) - mu * mu + 1e-5f);
  const float4 wv4 = ((const float4*)gw)[tid];
  const float4 bv4 = ((const float4*)gb)[tid];
  s16x4 o4;
  o4.x = f2b((v.x - mu) * rstd * wv4.x + bv4.x);
  o4.y = f2b((v.y - mu) * rstd * wv4.y + bv4.y);
  o4.z = f2b((v.z - mu) * rstd * wv4.z + bv4.z);
  o4.w = f2b((v.w - mu) * rstd * wv4.w + bv4.w);
  *(s16x4*)(out + (size_t)row * 1024 + tid * 4) = o4;
}

// ---------- layernorm, bf16 input: [rows][1024] bf16 -> bf16 ----------
__global__ __launch_bounds__(256) void ln_kernel_b(
    const short* __restrict__ x, const float* __restrict__ gw,
    const float* __restrict__ gb, short* __restrict__ out) {
  const int row = blockIdx.x;
  const int tid = threadIdx.x;
  const s16x4 xv = *(const s16x4*)(x + (size_t)row * 1024 + tid * 4);
  float v0 = b2f(xv.x), v1 = b2f(xv.y), v2 = b2f(xv.z), v3 = b2f(xv.w);
  float s = v0 + v1 + v2 + v3;
  float s2 = v0 * v0 + v1 * v1 + v2 * v2 + v3 * v3;
  #pragma unroll
  for (int o = 32; o > 0; o >>= 1) {
    s += __shfl_xor(s, o);
    s2 += __shfl_xor(s2, o);
  }
  __shared__ float red[2][4];
  const int lane = tid & 63, wid = tid >> 6;
  if (lane == 0) { red[0][wid] = s; red[1][wid] = s2; }
  __syncthreads();
  s = red[0][0] + red[0][1] + red[0][2] + red[0][3];
  s2 = red[1][0] + red[1][1] + red[1][2] + red[1][3];
  const float mu = s * (1.f / 1024.f);
  const float rstd = rsqrtf(s2 * (1.f / 1024.f) - mu * mu + 1e-5f);
  const float4 wv4 = ((const float4*)gw)[tid];
  const float4 bv4 = ((const float4*)gb)[tid];
  s16x4 o4;
  o4.x = f2b((v0 - mu) * rstd * wv4.x + bv4.x);
  o4.y = f2b((v1 - mu) * rstd * wv4.y + bv4.y);
  o4.z = f2b((v2 - mu) * rstd * wv4.z + bv4.z);
  o4.w = f2b((v3 - mu) * rstd * wv4.w + bv4.w);
  *(s16x4*)(out + (size_t)row * 1024 + tid * 4) = o4;
}

// ---------- 256x256 bf16 MFMA GEMM (r3-proven loop) + L2 super-tile mapping ----------
// GEMM loop byte-identical to r11/r12 (QKV 215us, MfmaUtil 43%, FETCH 156MB).
// r13 change is epilogue-only: residual path (src2) is now bf16 —
// EPI_RES writes bf16, EPI_FC2 reads bf16 resid (134->67MB x3 traffic cut).

enum { EPI_QKV = 0, EPI_RES = 1, EPI_GELU = 2, EPI_FC2 = 3 };

#define PHASE(BUFB, MH, KS, LOADB) do { \
    const int ab = (BUFB) + (KS) * 16384; \
    const int bb = (BUFB) + 32768 + (KS) * 16384; \
    if (LOADB) { \
      _Pragma("unroll") \
      for (int n = 0; n < 4; n++) { \
        const int row = wnCol + n * 16 + fr; \
        const int g = row >> 1; \
        const int s = (((row & 1) << 2) | fq) ^ (g & 7); \
        bfv[n] = *(const bf16x8*)(ldsc + bb + g * 128 + s * 16); \
      } \
    } \
    bf16x8 af[4]; \
    _Pragma("unroll") \
    for (int mm = 0; mm < 4; mm++) { \
      const int row = wmRow + (MH) * 64 + mm * 16 + fr; \
      const int g = row >> 1; \
      const int s = (((row & 1) << 2) | fq) ^ (g & 7); \
      af[mm] = *(const bf16x8*)(ldsc + ab + g * 128 + s * 16); \
    } \
    __builtin_amdgcn_s_setprio(1); \
    _Pragma("unroll") \
    for (int mm = 0; mm < 4; mm++) \
      _Pragma("unroll") \
      for (int n = 0; n < 4; n++) \
        acc[(MH) * 4 + mm][n] = __builtin_amdgcn_mfma_f32_16x16x32_bf16( \
            af[mm], bfv[n], acc[(MH) * 4 + mm][n], 0, 0, 0); \
    __builtin_amdgcn_s_setprio(0); \
  } while (0)

template <int EPI>
__global__ __launch_bounds__(512, 2) void gemm256(
    const short* __restrict__ A, int lda,
    const short* __restrict__ Bt, int K, int ldo, int gx,
    const float* __restrict__ bias,
    const void* __restrict__ resid,
    void* __restrict__ outp) {
  __shared__ alignas(16) short lds[65536];  // 128 KiB
  const int tid = threadIdx.x;
  const int lane = tid & 63, wave = tid >> 6;
  // T1: bijective XCD swizzle (grid % 8 == 0 for all launches)
  const int cpx = (int)gridDim.x >> 3;
  const int bid = ((int)blockIdx.x & 7) * cpx + ((int)blockIdx.x >> 3);
  // L2 super-tile mapping: 32-block groups of 8bm x 4bn
  const int sgx = gx >> 3;
  const int grp = bid >> 5;
  const int sm = grp % sgx, sn = grp / sgx;
  const int bm = (sm * 8 + (bid & 7)) * 256;
  const int bn = (sn * 4 + ((bid & 31) >> 3)) * 256;
  const int wmRow = (wave >> 2) * 128;
  const int wnCol = (wave & 3) * 64;
  const int fr = lane & 15, fq = lane >> 4;

  // staging constants: inverse-swizzled global source, linear LDS dest
  const int sg = tid >> 3;
  const int s0 = (tid & 7) ^ (sg & 7);
  const int srow = 2 * sg + (s0 >> 2);   // load 0 row; load 1 adds 128
  const int scol = (s0 & 3) * 8;
  const int sdst = tid * 16;

  const char* ldsc = (const char*)lds;
  char* ldsw = (char*)lds;

  f32x4 acc[8][4] = {};
  bf16x8 bfv[4];

  auto stageA = [&](int bufb, int kh, int kk) {
    const short* g = A + (size_t)(bm + srow) * lda + kk + kh * 32 + scol;
    char* l = ldsw + bufb + kh * 16384 + sdst;
    GLD16(g, l);
    GLD16(g + (size_t)128 * lda, l + 8192);
  };
  auto stageB = [&](int bufb, int kh, int kk) {
    const short* g = Bt + (size_t)(bn + srow) * K + kk + kh * 32 + scol;
    char* l = ldsw + bufb + 32768 + kh * 16384 + sdst;
    GLD16(g, l);
    GLD16(g + (size_t)128 * K, l + 8192);
  };

  const int NT = K >> 6;
  // prologue: full tile 0 into buf0; WAITB(4) -> kh0 proven, kh1 in flight
  stageA(0, 0, 0);
  stageB(0, 0, 0);
  stageA(0, 1, 0);
  stageB(0, 1, 0);
  WAITB(4);

  int buf = 0;
  for (int t = 0; t < NT; ++t) {
    const int kkn = (t + 1 < NT) ? ((t + 1) << 6) : 0;  // clamp keeps counts uniform
    const int nb = buf ^ 65536;
    stageA(nb, 0, kkn);
    PHASE(buf, 0, 0, true);
    stageB(nb, 0, kkn);
    PHASE(buf, 1, 0, false);
    WAITB(8);                       // kh1(t) proven (r3 ledger)
    stageA(nb, 1, kkn);
    PHASE(buf, 0, 1, true);
    stageB(nb, 1, kkn);
    PHASE(buf, 1, 1, false);
    WAITB(4);                       // kh0(t+1) proven; in-flight = kh1(t+1)
    buf = nb;
  }
  asm volatile("s_waitcnt vmcnt(0)" ::: "memory");

  // epilogue: row = bm+wmRow+m*16+fq*4+r ; col = bn+wnCol+n*16+fr
  const int row0 = bm + wmRow + fq * 4;
  const int col0 = bn + wnCol + fr;
  #pragma unroll
  for (int m = 0; m < 8; m++) {
    #pragma unroll
    for (int n = 0; n < 4; n++) {
      const int col = col0 + n * 16;
      #pragma unroll
      for (int r = 0; r < 4; r++) {
        const int row = row0 + m * 16 + r;
        float v = acc[m][n][r];
        if constexpr (EPI == EPI_QKV) {
          if (col < 2048) v = (v > 0.f) ? (v + 1.f) : __expf(v);  // phi = elu+1
          ((short*)outp)[(size_t)row * ldo + col] = f2b(v);
        } else if constexpr (EPI == EPI_RES) {
          // residual add (fp32 src) -> bf16 src2
          ((short*)outp)[(size_t)row * ldo + col] =
              f2b(v + ((const float*)resid)[(size_t)row * ldo + col]);
        } else if constexpr (EPI == EPI_GELU) {
          v += bias[col];
          v = 0.5f * v * (1.f + erff(v * 0.70710678118654752f));
          ((short*)outp)[(size_t)row * ldo + col] = f2b(v);
        } else {  // EPI_FC2: bias + bf16 residual -> fp32 d_out
          v += bias[col] + b2f(((const short*)resid)[(size_t)row * ldo + col]);
          ((float*)outp)[(size_t)row * ldo + col] = v;
        }
      }
    }
  }
}

// ---------- kv partial reduce v2: fp32 LDS tiles (r12) ----------
__global__ __launch_bounds__(256) void kv_reduce(
    const short* __restrict__ qkv, float* __restrict__ kv_part,
    float* __restrict__ ksum_part) {
  const int blk = blockIdx.x;  // 4096 = 64 bh * 64 chunks
  const int bh = blk >> 6, chunk = blk & 63;
  const int b = bh >> 4, h = bh & 15;
  const size_t rowbase = (size_t)b * 8192 + (size_t)chunk * 128;
  const int kcol = 1024 + h * 64, vcol = 2048 + h * 64;
  __shared__ float Klf[64][68];
  __shared__ float Vlf[64][68];
  const int tid = threadIdx.x;
  const int dk = tid >> 2, dq = tid & 3;
  float acc[16] = {};
  float ks = 0.f;
  for (int t = 0; t < 2; t++) {
    #pragma unroll
    for (int i = 0; i < 2; i++) {
      const int s = i * 256 + tid;
      const int r = s >> 3, seg = (s & 7) * 8;
      const size_t g = (rowbase + t * 64 + r) * 3072;
      const s16x8 k8 = *(const s16x8*)&qkv[g + kcol + seg];
      const s16x8 v8 = *(const s16x8*)&qkv[g + vcol + seg];
      float4 ka, kb, va, vb;
      ka.x = b2f(k8[0]); ka.y = b2f(k8[1]); ka.z = b2f(k8[2]); ka.w = b2f(k8[3]);
      kb.x = b2f(k8[4]); kb.y = b2f(k8[5]); kb.z = b2f(k8[6]); kb.w = b2f(k8[7]);
      va.x = b2f(v8[0]); va.y = b2f(v8[1]); va.z = b2f(v8[2]); va.w = b2f(v8[3]);
      vb.x = b2f(v8[4]); vb.y = b2f(v8[5]); vb.z = b2f(v8[6]); vb.w = b2f(v8[7]);
      *(float4*)&Klf[r][seg] = ka;
      *(float4*)&Klf[r][seg + 4] = kb;
      *(float4*)&Vlf[r][seg] = va;
      *(float4*)&Vlf[r][seg + 4] = vb;
    }
    __syncthreads();
    #pragma unroll 4
    for (int n = 0; n < 64; n++) {
      const float kval = Klf[n][dk];
      if (dq == 0) ks += kval;
      const float4 v0 = *(const float4*)&Vlf[n][dq * 16];
      const float4 v1 = *(const float4*)&Vlf[n][dq * 16 + 4];
      const float4 v2 = *(const float4*)&Vlf[n][dq * 16 + 8];
      const float4 v3 = *(const float4*)&Vlf[n][dq * 16 + 12];
      acc[0]  = fmaf(kval, v0.x, acc[0]);
      acc[1]  = fmaf(kval, v0.y, acc[1]);
      acc[2]  = fmaf(kval, v0.z, acc[2]);
      acc[3]  = fmaf(kval, v0.w, acc[3]);
      acc[4]  = fmaf(kval, v1.x, acc[4]);
      acc[5]  = fmaf(kval, v1.y, acc[5]);
      acc[6]  = fmaf(kval, v1.z, acc[6]);
      acc[7]  = fmaf(kval, v1.w, acc[7]);
      acc[8]  = fmaf(kval, v2.x, acc[8]);
      acc[9]  = fmaf(kval, v2.y, acc[9]);
      acc[10] = fmaf(kval, v2.z, acc[10]);
      acc[11] = fmaf(kval, v2.w, acc[11]);
      acc[12] = fmaf(kval, v3.x, acc[12]);
      acc[13] = fmaf(kval, v3.y, acc[13]);
      acc[14] = fmaf(kval, v3.z, acc[14]);
      acc[15] = fmaf(kval, v3.w, acc[15]);
    }
    __syncthreads();
  }
  float* dst = kv_part + (size_t)blk * 4096 + dk * 64 + dq * 16;
  #pragma unroll
  for (int j = 0; j < 16; j++) dst[j] = acc[j];
  if (dq == 0) ksum_part[(size_t)blk * 64 + dk] = ks;
}

// ---------- kv finalize: reduce 64 partials -> bf16 kv^T, pre-swizzled ----------
__global__ __launch_bounds__(256) void kv_finalize(
    const float* __restrict__ kv_part, const float* __restrict__ ksum_part,
    short* __restrict__ kvT_g, float* __restrict__ ksum_f) {
  const int bh = blockIdx.x >> 2, dg = blockIdx.x & 3;
  const int tid = threadIdx.x;
  const int e = tid & 63, j4 = tid >> 6;
  const int d0 = dg * 16 + j4 * 4;
  float a0 = 0.f, a1 = 0.f, a2 = 0.f, a3 = 0.f;
  const float* base = kv_part + (size_t)bh * 64 * 4096 + d0 * 64 + e;
  for (int c = 0; c < 64; c++) {
    const float* p = base + (size_t)c * 4096;
    a0 += p[0]; a1 += p[64]; a2 += p[128]; a3 += p[192];
  }
  s16x4 o; o.x = f2b(a0); o.y = f2b(a1); o.z = f2b(a2); o.w = f2b(a3);
  char* dstb = (char*)(kvT_g + (size_t)bh * 4096);
  *(s16x4*)(dstb + e * 128 + ((2 * d0) ^ ((e & 7) << 4))) = o;
  if (tid < 16) {
    const int d = dg * 16 + tid;
    float s = 0.f;
    for (int c = 0; c < 64; c++)
      s += ksum_part[((size_t)bh * 64 + c) * 64 + d];
    ksum_f[bh * 64 + d] = s;
  }
}

// ---------- attention apply via MFMA: ao = (Q @ kv) / (Q . ksum + eps) ----------
__global__ __launch_bounds__(256) void attn_apply_mfma(
    const short* __restrict__ qkv, const short* __restrict__ kvT_g,
    const float* __restrict__ ksum_f, short* __restrict__ ao) {
  __shared__ alignas(16) short kvs[4096];
  __shared__ float ksl[64];
  const int blk = blockIdx.x;
  const int bh = blk >> 5, rc = blk & 31;
  const int b = bh >> 4, h = bh & 15;
  const int tid = threadIdx.x, lane = tid & 63, w = tid >> 6;
  const int fr = lane & 15, fq = lane >> 4;

  GLD16(kvT_g + (size_t)bh * 4096 + tid * 8, (char*)kvs + tid * 16);
  GLD16(kvT_g + (size_t)bh * 4096 + (256 + tid) * 8, (char*)kvs + (256 + tid) * 16);
  if (tid < 64) ksl[tid] = ksum_f[bh * 64 + tid];
  __syncthreads();

  bf16x8 bkv[4][2], bns[2];
  #pragma unroll
  for (int n = 0; n < 4; n++) {
    #pragma unroll
    for (int c = 0; c < 2; c++) {
      const int e = n * 16 + fr;
      const int byteoff = e * 128 + ((c * 64 + fq * 16) ^ ((e & 7) << 4));
      bkv[n][c] = *(const bf16x8*)((const char*)kvs + byteoff);
    }
  }
  #pragma unroll
  for (int c = 0; c < 2; c++) {
    s16x8 ts = {0, 0, 0, 0, 0, 0, 0, 0};
    if (fr == 0) {
      #pragma unroll
      for (int j = 0; j < 8; j++) ts[j] = f2b(ksl[c * 32 + fq * 8 + j]);
    }
    bns[c] = asbf(ts);
  }

  f32x4 acc[4][4] = {};
  f32x4 nacc[4] = {};
  const size_t rowbase = (size_t)b * 8192 + (size_t)rc * 256 + w * 64;
  const int qcol = h * 64;
  #pragma unroll
  for (int m = 0; m < 4; m++) {
    const short* qrow = qkv + (rowbase + m * 16 + fr) * 3072 + qcol + fq * 8;
    const bf16x8 a0 = *(const bf16x8*)qrow;
    const bf16x8 a1 = *(const bf16x8*)(qrow + 32);
    #pragma unroll
    for (int n = 0; n < 4; n++) {
      acc[m][n] = __builtin_amdgcn_mfma_f32_16x16x32_bf16(a0, bkv[n][0], acc[m][n], 0, 0, 0);
      acc[m][n] = __builtin_amdgcn_mfma_f32_16x16x32_bf16(a1, bkv[n][1], acc[m][n], 0, 0, 0);
    }
    nacc[m] = __builtin_amdgcn_mfma_f32_16x16x32_bf16(a0, bns[0], nacc[m], 0, 0, 0);
    nacc[m] = __builtin_amdgcn_mfma_f32_16x16x32_bf16(a1, bns[1], nacc[m], 0, 0, 0);
  }

  #pragma unroll
  for (int m = 0; m < 4; m++) {
    #pragma unroll
    for (int r = 0; r < 4; r++) {
      const float nv = __shfl(nacc[m][r], lane & 48) + 1e-6f;
      const float rn = 1.f / nv;
      const size_t row = rowbase + m * 16 + fq * 4 + r;
      #pragma unroll
      for (int n = 0; n < 4; n++)
        ao[row * 1024 + qcol + n * 16 + fr] = f2b(acc[m][n][r] * rn);
    }
  }
}

// ---------- launcher ----------
extern "C" void kernel_launch(void* const* d_in, const int* in_sizes, int n_in,
                              void* d_out, int out_size, void* d_ws, size_t ws_size,
                              hipStream_t stream) {
  (void)in_sizes; (void)n_in; (void)out_size; (void)ws_size;
  const float* src   = (const float*)d_in[0];
  const float* ln1_w = (const float*)d_in[1];
  const float* ln1_b = (const float*)d_in[2];
  const float* wq    = (const float*)d_in[3];
  const float* wk    = (const float*)d_in[4];
  const float* wv    = (const float*)d_in[5];
  const float* wo    = (const float*)d_in[6];
  const float* ln2_w = (const float*)d_in[7];
  const float* ln2_b = (const float*)d_in[8];
  const float* fc1_w = (const float*)d_in[9];
  const float* fc1_b = (const float*)d_in[10];
  const float* fc2_w = (const float*)d_in[11];
  const float* fc2_b = (const float*)d_in[12];

  char* ws = (char*)d_ws;
  short* wqkvT     = (short*)(ws + 0);            // [3072][1024] bf16
  short* woT       = (short*)(ws + 6291456);      // [1024][1024]
  short* fc1T      = (short*)(ws + 8388608);      // [4096][1024]
  short* fc2T      = (short*)(ws + 16777216);     // [1024][4096]
  short* kvT_g     = (short*)(ws + 25165824);     // [64][4096] bf16 swizzled
  float* ksum_f    = (float*)(ws + 25690112);     // [64][64]
  float* kv_part   = (float*)(ws + 25706496);     // [4096][4096] fp32 (67.1MB)
  float* ksum_part = (float*)(ws + 92815360);     // [4096][64]
  short* hbuf      = (short*)(ws + 93863936);     // [32768][1024] bf16 (h / ao / h2)
  short* src2b     = (short*)(ws + 160972800);    // [32768][1024] bf16 (residual)
  short* qkv       = (short*)(ws + 295190528);    // [32768][3072] bf16
  short* a1c       = (short*)(ws + 295190528);    // [16384][4096] bf16 (aliases qkv)
  // high-water: 496,517,120 bytes (< 503,447,552 proven in round 1)

  const dim3 tb(256);
  const dim3 tb512(512);

  // weights -> bf16 transposed
  transpose_cvt<<<dim3(32, 32), tb, 0, stream>>>(wq, wqkvT, 1024, 1024);
  transpose_cvt<<<dim3(32, 32), tb, 0, stream>>>(wk, wqkvT + 1024 * 1024, 1024, 1024);
  transpose_cvt<<<dim3(32, 32), tb, 0, stream>>>(wv, wqkvT + 2048 * 1024, 1024, 1024);
  transpose_cvt<<<dim3(32, 32), tb, 0, stream>>>(wo, woT, 1024, 1024);
  transpose_cvt<<<dim3(128, 32), tb, 0, stream>>>(fc1_w, fc1T, 1024, 4096);
  transpose_cvt<<<dim3(32, 128), tb, 0, stream>>>(fc2_w, fc2T, 4096, 1024);

  // LN1: src (fp32) -> h (bf16)
  ln_kernel<<<32768, tb, 0, stream>>>(src, ln1_w, ln1_b, hbuf);

  // QKV projection + phi on Q,K   (M=32768, N=3072, K=1024; gx=128, gy=12)
  gemm256<EPI_QKV><<<dim3(1536), tb512, 0, stream>>>(
      hbuf, 1024, wqkvT, 1024, 3072, 128, nullptr, nullptr, qkv);

  // kv / ksum: partial reduce (v2) -> finalize (bf16, transposed, swizzled)
  kv_reduce<<<4096, tb, 0, stream>>>(qkv, kv_part, ksum_part);
  kv_finalize<<<256, tb, 0, stream>>>(kv_part, ksum_part, kvT_g, ksum_f);

  // attention apply via MFMA -> ao (hbuf)
  attn_apply_mfma<<<2048, tb, 0, stream>>>(qkv, kvT_g, ksum_f, hbuf);

  // O projection + residual(src fp32) -> src2b (bf16)  (gx=128, gy=4)
  gemm256<EPI_RES><<<dim3(512), tb512, 0, stream>>>(
      hbuf, 1024, woT, 1024, 1024, 128, nullptr, src, src2b);

  // LN2: src2b (bf16) -> h2 (bf16, reuse hbuf)
  ln_kernel_b<<<32768, tb, 0, stream>>>(src2b, ln2_w, ln2_b, hbuf);

  // MLP, 2 chunks of 16384 rows (a1c aliases dead qkv buffer)
  for (int c = 0; c < 2; c++) {
    const size_t mo = (size_t)c * 16384;
    // FC1: M=16384, N=4096, K=1024; gx=64, gy=16
    gemm256<EPI_GELU><<<dim3(1024), tb512, 0, stream>>>(
        hbuf + mo * 1024, 1024, fc1T, 1024, 4096, 64, fc1_b, nullptr, a1c);
    // FC2: M=16384, N=1024, K=4096; gx=64, gy=4 ; bf16 residual
    gemm256<EPI_FC2><<<dim3(256), tb512, 0, stream>>>(
        a1c, 4096, fc2T, 4096, 1024, 64, fc2_b, src2b + mo * 1024,
        (float*)d_out + mo * 1024);
  }
}